// Round 4
// baseline (1534.328 us; speedup 1.0000x reference)
//
#include <hip/hip_runtime.h>

#define N_NODES 50000
#define N_EDGES 800000
#define D_FEAT 128
#define LN_EPS 1e-5f
#define NPB 16   // nodes per block in the main kernel

// ---------------------------------------------------------------------------
// Kernel 0: zero the accumulation workspace (ws is poisoned 0xAA every call).
// ---------------------------------------------------------------------------
__global__ void zero_kernel(float* __restrict__ p, int n)
{
    int i = blockIdx.x * 256 + threadIdx.x;
    if (i < n) p[i] = 0.0f;
}

// ---------------------------------------------------------------------------
// Kernel 1: edge scatter. One 64-lane wave per edge; each lane adds 2 feats.
// nbr_sum[dst] += x[src]; deg[dst] += 1
// ---------------------------------------------------------------------------
__global__ void scatter_kernel(
        const float* __restrict__ x,
        const int* __restrict__ ei,
        float* __restrict__ nbr_sum,
        float* __restrict__ deg)
{
    int gid  = blockIdx.x * 256 + threadIdx.x;
    int e    = gid >> 6;
    int lane = threadIdx.x & 63;
    if (e >= N_EDGES) return;
    int src = ei[e];              // row (feature source)
    int dst = ei[N_EDGES + e];    // col (scatter destination)
    src = (src < 0) ? 0 : ((src >= N_NODES) ? (N_NODES - 1) : src);
    dst = (dst < 0) ? 0 : ((dst >= N_NODES) ? (N_NODES - 1) : dst);

    float f0 = x[src * D_FEAT + lane * 2];
    float f1 = x[src * D_FEAT + lane * 2 + 1];
    atomicAdd(&nbr_sum[dst * D_FEAT + lane * 2],     f0);
    atomicAdd(&nbr_sum[dst * D_FEAT + lane * 2 + 1], f1);
    if (lane == 0) atomicAdd(&deg[dst], 1.0f);
}

// ---------------------------------------------------------------------------
// Kernel 2: weight prep. Block n (of 128) builds row n of the fused weight
// Wtf[n][k]: k<128 -> W1[k][n]; k>=128 -> M[k-128][n], where M = agg_W @ W2
// (algebra: concat([x,agg]) @ W == x@W1 + agg@(agg_W@W2) + agg_b@W2).
// cvec[n] = b[n] + sum_j agg_b[j]*W2[j][n].
// ---------------------------------------------------------------------------
__global__ void wprep_kernel(
        const float* __restrict__ agg_W,
        const float* __restrict__ agg_b,
        const float* __restrict__ W,
        const float* __restrict__ b,
        float* __restrict__ Wtf,
        float* __restrict__ cvec)
{
    __shared__ float w2col[128];
    int n = blockIdx.x;
    int t = threadIdx.x;

    w2col[t] = W[(128 + t) * 128 + n];   // W2 column n
    __syncthreads();

    Wtf[n * 256 + t] = W[t * 128 + n];   // W1 transposed

    float m = 0.0f;
    for (int j = 0; j < 128; ++j)
        m += agg_W[t * 128 + j] * w2col[j];
    Wtf[n * 256 + 128 + t] = m;

    if (t == 0) {
        float s = b[n];
        for (int j = 0; j < 128; ++j)
            s += agg_b[j] * w2col[j];
        cvec[n] = s;
    }
}

// ---------------------------------------------------------------------------
// Kernel 3: fused (x@W1 + agg@M + c) -> ReLU -> LayerNorm -> fp32 out.
// Vector-ALU version: 256 threads, NPB=16 nodes per block.
// ---------------------------------------------------------------------------
__global__ void gsage_main(
        const float* __restrict__ x,
        const float* __restrict__ nbr_sum,
        const float* __restrict__ deg,
        const float* __restrict__ Wtf,
        const float* __restrict__ cvec,
        const float* __restrict__ gamma,
        const float* __restrict__ beta,
        float* __restrict__ out)
{
    __shared__ float cf[NPB][256];     // concat rows [x | agg], fp32
    __shared__ float vals[NPB][128];   // post-ReLU values
    __shared__ float mu_s[NPB], rs_s[NPB];

    int tid   = threadIdx.x;
    int node0 = blockIdx.x * NPB;

    // stage concat rows
    for (int idx = tid; idx < NPB * 256; idx += 256) {
        int nl = idx >> 8, k = idx & 255;
        int node = node0 + nl;
        float v = 0.0f;
        if (node < N_NODES) {
            if (k < 128) {
                v = x[node * D_FEAT + k];
            } else {
                float dg = deg[node];
                if (dg < 1.0f) dg = 1.0f;
                v = nbr_sum[node * D_FEAT + (k - 128)] / dg;
            }
        }
        cf[nl][k] = v;
    }
    __syncthreads();

    // GEMV: each thread produces 8 outputs (node_local, col)
    for (int o = 0; o < (NPB * 128) / 256; ++o) {
        int idx = o * 256 + tid;
        int nl = idx >> 7, col = idx & 127;
        float acc = cvec[col];
        const float* wr = Wtf + col * 256;
        for (int k = 0; k < 256; ++k) acc += cf[nl][k] * wr[k];
        vals[nl][col] = (acc > 0.0f) ? acc : 0.0f;
    }
    __syncthreads();

    // LN stats, one thread per node
    if (tid < NPB) {
        float s1 = 0.0f, s2 = 0.0f;
        for (int k = 0; k < 128; ++k) {
            float v = vals[tid][k];
            s1 += v; s2 += v * v;
        }
        float mu  = s1 * (1.0f / 128.0f);
        float var = s2 * (1.0f / 128.0f) - mu * mu;
        mu_s[tid] = mu;
        rs_s[tid] = rsqrtf(var + LN_EPS);
    }
    __syncthreads();

    // normalize + store
    for (int o = 0; o < (NPB * 128) / 256; ++o) {
        int idx = o * 256 + tid;
        int nl = idx >> 7, col = idx & 127;
        int node = node0 + nl;
        if (node < N_NODES) {
            float v = (vals[nl][col] - mu_s[nl]) * rs_s[nl] * gamma[col] + beta[col];
            out[node * D_FEAT + col] = v;
        }
    }
}

// ---------------------------------------------------------------------------
// Launcher with self-diagnosis: on structural mismatch or launch error, fill
// d_out with a decodable memset pattern (shows up in the reported absmax).
//   0x40 -> 3.004     : launcher ran; kernels launched "ok" but wrote nothing
//   0x45 -> ~3152     : n_in != 8
//   0x46 -> ~12672    : ws_size too small
//   0x47 -> ~50944    : out_size unexpected
//   0x48 -> ~2.05e5   : in_sizes[0] (x) unexpected
//   0x49 -> ~8.2e5    : in_sizes[1] (edge_index) unexpected
//   0x50+k -> >=1e10  : a kernel launch returned error code with (code&15)==k
// ---------------------------------------------------------------------------
extern "C" void kernel_launch(void* const* d_in, const int* in_sizes, int n_in,
                              void* d_out, int out_size, void* d_ws, size_t ws_size,
                              hipStream_t stream) {
    const float* x     = (const float*)d_in[0];
    const int*   ei    = (const int*)d_in[1];
    const float* agg_W = (const float*)d_in[2];
    const float* agg_b = (const float*)d_in[3];
    const float* W     = (const float*)d_in[4];
    const float* b     = (const float*)d_in[5];
    const float* gamma = (const float*)d_in[6];
    const float* beta  = (const float*)d_in[7];
    float*       out   = (float*)d_out;

    size_t out_bytes = (size_t)out_size * sizeof(float);
    (void)hipGetLastError();   // clear any sticky error

    // marker: proves kernel_launch executed even if no kernel runs
    hipMemsetAsync(d_out, 0x40, out_bytes, stream);

    if (n_in != 8)                      { hipMemsetAsync(d_out, 0x45, out_bytes, stream); return; }
    if (in_sizes[0] != N_NODES * D_FEAT){ hipMemsetAsync(d_out, 0x48, out_bytes, stream); return; }
    if (in_sizes[1] != 2 * N_EDGES)     { hipMemsetAsync(d_out, 0x49, out_bytes, stream); return; }
    if (out_size != N_NODES * D_FEAT)   { hipMemsetAsync(d_out, 0x47, out_bytes, stream); return; }
    size_t need_ws = ((size_t)N_NODES * D_FEAT + N_NODES + 256 * 128 + 128) * sizeof(float);
    if (ws_size < need_ws)              { hipMemsetAsync(d_out, 0x46, out_bytes, stream); return; }

    // workspace layout (all fp32)
    float* nbr_sum = (float*)d_ws;                        // 50000*128
    float* deg     = nbr_sum + (size_t)N_NODES * D_FEAT;  // 50000
    float* Wtf     = deg + N_NODES;                       // 256*128 (fused W, transposed)
    float* cvec    = Wtf + 256 * 128;                     // 128

    int nzero = N_NODES * D_FEAT + N_NODES;               // nbr_sum + deg
    zero_kernel<<<(nzero + 255) / 256, 256, 0, stream>>>(nbr_sum, nzero);
    scatter_kernel<<<(N_EDGES * 64) / 256, 256, 0, stream>>>(x, ei, nbr_sum, deg);
    wprep_kernel<<<128, 128, 0, stream>>>(agg_W, agg_b, W, b, Wtf, cvec);
    gsage_main<<<(N_NODES + NPB - 1) / NPB, 256, 0, stream>>>(
        x, nbr_sum, deg, Wtf, cvec, gamma, beta, out);

    hipError_t e = hipGetLastError();
    if (e != hipSuccess) {
        hipMemsetAsync(d_out, (int)(0x50 + ((int)e & 15)), out_bytes, stream);
    }
}

// Round 5
// 387.867 us; speedup vs baseline: 3.9558x; 3.9558x over previous
//
#include <hip/hip_runtime.h>

#define N_NODES 50000
#define N_EDGES 800000
#define D_FEAT 128
#define LN_EPS 1e-5f
#define TM 32          // nodes per block in gsage_main
#define KB 32          // K-chunk
#define APAD 36        // padded A-tile row stride (floats), keeps 16B alignment

// ---------------------------------------------------------------------------
// zero the degree counters (ws is poisoned 0xAA every call)
// ---------------------------------------------------------------------------
__global__ void zero_kernel(int* __restrict__ p, int n)
{
    int i = blockIdx.x * 256 + threadIdx.x;
    if (i < n) p[i] = 0;
}

// ---------------------------------------------------------------------------
// histogram of destination nodes
// ---------------------------------------------------------------------------
__global__ void hist_kernel(const int* __restrict__ ei, int* __restrict__ deg_cnt)
{
    int e = blockIdx.x * 256 + threadIdx.x;
    if (e >= N_EDGES) return;
    int dst = ei[N_EDGES + e];
    dst = (dst < 0) ? 0 : ((dst >= N_NODES) ? (N_NODES - 1) : dst);
    atomicAdd(&deg_cnt[dst], 1);
}

// ---------------------------------------------------------------------------
// exclusive prefix-sum of deg_cnt -> pos  (single block, 1024 threads)
// ---------------------------------------------------------------------------
__global__ void scan_kernel(const int* __restrict__ deg_cnt, int* __restrict__ pos)
{
    __shared__ int sums[1024];
    const int PER = (N_NODES + 1023) / 1024;   // 49
    int t = threadIdx.x;
    int base = t * PER;

    int s = 0;
    for (int i = 0; i < PER; ++i) {
        int idx = base + i;
        if (idx < N_NODES) s += deg_cnt[idx];
    }
    sums[t] = s;
    __syncthreads();
    for (int off = 1; off < 1024; off <<= 1) {
        int v = 0;
        if (t >= off) v = sums[t - off];
        __syncthreads();
        sums[t] += v;
        __syncthreads();
    }
    int acc = sums[t] - s;   // exclusive base for this thread's range
    for (int i = 0; i < PER; ++i) {
        int idx = base + i;
        if (idx < N_NODES) {
            pos[idx] = acc;
            acc += deg_cnt[idx];
        }
    }
}

// ---------------------------------------------------------------------------
// bucket fill: edge_src[slot] = src, slot = pos[dst]++  (after this, pos = end)
// ---------------------------------------------------------------------------
__global__ void fill_kernel(const int* __restrict__ ei, int* __restrict__ pos,
                            int* __restrict__ edge_src)
{
    int e = blockIdx.x * 256 + threadIdx.x;
    if (e >= N_EDGES) return;
    int src = ei[e];
    int dst = ei[N_EDGES + e];
    src = (src < 0) ? 0 : ((src >= N_NODES) ? (N_NODES - 1) : src);
    dst = (dst < 0) ? 0 : ((dst >= N_NODES) ? (N_NODES - 1) : dst);
    int slot = atomicAdd(&pos[dst], 1);
    edge_src[slot] = src;
}

// ---------------------------------------------------------------------------
// gather: one 64-lane wave per node; agg mean written into d_out (scratch).
// Lane holds 2 features (float2); edge ids broadcast via shfl from a
// coalesced 64-edge batch load.
// ---------------------------------------------------------------------------
__global__ void gather_kernel(const float* __restrict__ x,
                              const int* __restrict__ pos,      // = end after fill
                              const int* __restrict__ deg_cnt,
                              const int* __restrict__ edge_src,
                              float* __restrict__ agg)          // d_out scratch
{
    int tid  = threadIdx.x;
    int node = blockIdx.x * 4 + (tid >> 6);
    int lane = tid & 63;
    if (node >= N_NODES) return;

    int end   = pos[node];
    int dcnt  = deg_cnt[node];
    int start = end - dcnt;

    float a0 = 0.0f, a1 = 0.0f;
    for (int b = start; b < end; b += 64) {
        int nb = end - b; if (nb > 64) nb = 64;
        int sid = (b + lane < end) ? edge_src[b + lane] : 0;
        for (int i = 0; i < nb; ++i) {
            int s = __shfl(sid, i, 64);
            const float2 v = *(const float2*)(x + (size_t)s * D_FEAT + lane * 2);
            a0 += v.x; a1 += v.y;
        }
    }
    float inv = 1.0f / (float)((dcnt > 1) ? dcnt : 1);
    agg[(size_t)node * D_FEAT + lane * 2]     = a0 * inv;
    agg[(size_t)node * D_FEAT + lane * 2 + 1] = a1 * inv;
}

// ---------------------------------------------------------------------------
// weight prep.  Wt2 layout [k][n], k<128 -> W1 (verbatim copy of W's first
// half); k>=128 -> M = agg_W @ W2.  Block t builds row t of both halves.
// Block 0 additionally builds cvec[n] = b[n] + sum_j agg_b[j]*W2[j][n].
// ---------------------------------------------------------------------------
__global__ void wprep_kernel(const float* __restrict__ agg_W,
                             const float* __restrict__ agg_b,
                             const float* __restrict__ W,
                             const float* __restrict__ b,
                             float* __restrict__ Wt2,
                             float* __restrict__ cvec)
{
    int t = blockIdx.x;    // 0..127
    int n = threadIdx.x;   // 0..127

    Wt2[t * 128 + n] = W[t * 128 + n];            // W1 half, already [k][n]

    float m = 0.0f;
    for (int j = 0; j < 128; ++j)
        m += agg_W[t * 128 + j] * W[(128 + j) * 128 + n];
    Wt2[(128 + t) * 128 + n] = m;

    if (t == 0) {
        float s = b[n];
        for (int j = 0; j < 128; ++j)
            s += agg_b[j] * W[(128 + j) * 128 + n];
        cvec[n] = s;
    }
}

// ---------------------------------------------------------------------------
// fused GEMM (A=[x|agg] @ Wt2^T + c) -> ReLU -> LayerNorm -> out (fp32).
// 256 threads, 32 nodes/block; K=256 chunked by 32; A + W chunks in LDS.
// Thread (tx=tid&31, ty=tid>>5) owns 4 nodes (ty*4..) x 4 cols (tx*4..).
// NOTE: reads agg rows from d_out and later overwrites the same rows; safe
// because each block only touches its own 32 nodes and all reads precede
// the epilogue stores.
// ---------------------------------------------------------------------------
__global__ __launch_bounds__(256) void gsage_main(
        const float* __restrict__ x,
        const float* __restrict__ agg,      // aliases `out`
        const float* __restrict__ Wt2,
        const float* __restrict__ cvec,
        const float* __restrict__ gamma,
        const float* __restrict__ beta,
        float* __restrict__ out)
{
    __shared__ float A[TM][APAD];     // 32 x 36 floats
    __shared__ float Wc[KB * 128];    // 32 x 128 floats

    int tid   = threadIdx.x;
    int tx    = tid & 31;
    int ty    = tid >> 5;
    int node0 = blockIdx.x * TM;

    float acc[4][4];
    #pragma unroll
    for (int i = 0; i < 4; ++i)
        #pragma unroll
        for (int j = 0; j < 4; ++j) acc[i][j] = 0.0f;

    for (int c = 0; c < 256 / KB; ++c) {
        int k0 = c * KB;
        // ---- stage A chunk: node = tid>>3, kk = (tid&7)*4 ----
        {
            int r  = tid >> 3;
            int kk = (tid & 7) * 4;
            int k  = k0 + kk;
            int node = node0 + r;
            float4 v = make_float4(0.f, 0.f, 0.f, 0.f);
            if (node < N_NODES) {
                const float* src = (k < 128)
                    ? (x   + (size_t)node * D_FEAT + k)
                    : (agg + (size_t)node * D_FEAT + (k - 128));
                v = *(const float4*)src;
            }
            *(float4*)&A[r][kk] = v;
        }
        // ---- stage W chunk: rows k0..k0+31 of Wt2, 16 KB contiguous ----
        {
            const float4* src = (const float4*)(Wt2 + k0 * 128);
            float4* dstp = (float4*)Wc;
            #pragma unroll
            for (int i = 0; i < 4; ++i)
                dstp[i * 256 + tid] = src[i * 256 + tid];
        }
        __syncthreads();

        // ---- inner product ----
        #pragma unroll 8
        for (int kk = 0; kk < KB; ++kk) {
            float a0 = A[ty * 4 + 0][kk];
            float a1 = A[ty * 4 + 1][kk];
            float a2 = A[ty * 4 + 2][kk];
            float a3 = A[ty * 4 + 3][kk];
            float4 w = *(const float4*)&Wc[kk * 128 + tx * 4];
            acc[0][0] += a0 * w.x; acc[0][1] += a0 * w.y; acc[0][2] += a0 * w.z; acc[0][3] += a0 * w.w;
            acc[1][0] += a1 * w.x; acc[1][1] += a1 * w.y; acc[1][2] += a1 * w.z; acc[1][3] += a1 * w.w;
            acc[2][0] += a2 * w.x; acc[2][1] += a2 * w.y; acc[2][2] += a2 * w.z; acc[2][3] += a2 * w.w;
            acc[3][0] += a3 * w.x; acc[3][1] += a3 * w.y; acc[3][2] += a3 * w.z; acc[3][3] += a3 * w.w;
        }
        __syncthreads();
    }

    // ---- epilogue: +c, ReLU, LayerNorm over 128 cols (32 tx lanes) ----
    float4 cv = *(const float4*)(cvec  + tx * 4);
    float4 gv = *(const float4*)(gamma + tx * 4);
    float4 bv = *(const float4*)(beta  + tx * 4);

    #pragma unroll
    for (int i = 0; i < 4; ++i) {
        float v0 = acc[i][0] + cv.x; v0 = (v0 > 0.f) ? v0 : 0.f;
        float v1 = acc[i][1] + cv.y; v1 = (v1 > 0.f) ? v1 : 0.f;
        float v2 = acc[i][2] + cv.z; v2 = (v2 > 0.f) ? v2 : 0.f;
        float v3 = acc[i][3] + cv.w; v3 = (v3 > 0.f) ? v3 : 0.f;
        float s1 = v0 + v1 + v2 + v3;
        float s2 = v0*v0 + v1*v1 + v2*v2 + v3*v3;
        #pragma unroll
        for (int m = 1; m < 32; m <<= 1) {
            s1 += __shfl_xor(s1, m, 64);
            s2 += __shfl_xor(s2, m, 64);
        }
        float mu  = s1 * (1.0f / 128.0f);
        float var = s2 * (1.0f / 128.0f) - mu * mu;
        float rstd = rsqrtf(var + LN_EPS);
        int node = node0 + ty * 4 + i;
        if (node < N_NODES) {
            float4 o;
            o.x = (v0 - mu) * rstd * gv.x + bv.x;
            o.y = (v1 - mu) * rstd * gv.y + bv.y;
            o.z = (v2 - mu) * rstd * gv.z + bv.z;
            o.w = (v3 - mu) * rstd * gv.w + bv.w;
            *(float4*)(out + (size_t)node * D_FEAT + tx * 4) = o;
        }
    }
}

// ---------------------------------------------------------------------------
extern "C" void kernel_launch(void* const* d_in, const int* in_sizes, int n_in,
                              void* d_out, int out_size, void* d_ws, size_t ws_size,
                              hipStream_t stream) {
    const float* x     = (const float*)d_in[0];
    const int*   ei    = (const int*)d_in[1];
    const float* agg_W = (const float*)d_in[2];
    const float* agg_b = (const float*)d_in[3];
    const float* W     = (const float*)d_in[4];
    const float* b     = (const float*)d_in[5];
    const float* gamma = (const float*)d_in[6];
    const float* beta  = (const float*)d_in[7];
    float*       out   = (float*)d_out;

    size_t out_bytes = (size_t)out_size * sizeof(float);

    if (n_in != 8)                       { hipMemsetAsync(d_out, 0x45, out_bytes, stream); return; }
    if (in_sizes[0] != N_NODES * D_FEAT) { hipMemsetAsync(d_out, 0x48, out_bytes, stream); return; }
    if (in_sizes[1] != 2 * N_EDGES)      { hipMemsetAsync(d_out, 0x49, out_bytes, stream); return; }
    if (out_size != N_NODES * D_FEAT)    { hipMemsetAsync(d_out, 0x47, out_bytes, stream); return; }

    // workspace layout (4-byte elements)
    int*   deg_cnt  = (int*)d_ws;                  // 50000
    int*   pos      = deg_cnt + N_NODES;           // 50000
    int*   edge_src = pos + N_NODES;               // 800000
    float* Wt2      = (float*)(edge_src + N_EDGES);// 256*128
    float* cvec     = Wt2 + 256 * 128;             // 128
    size_t need_ws = ((size_t)N_NODES * 2 + N_EDGES + 256 * 128 + 128) * 4;
    if (ws_size < need_ws)               { hipMemsetAsync(d_out, 0x46, out_bytes, stream); return; }

    zero_kernel<<<(N_NODES + 255) / 256, 256, 0, stream>>>(deg_cnt, N_NODES);
    hist_kernel<<<(N_EDGES + 255) / 256, 256, 0, stream>>>(ei, deg_cnt);
    scan_kernel<<<1, 1024, 0, stream>>>(deg_cnt, pos);
    fill_kernel<<<(N_EDGES + 255) / 256, 256, 0, stream>>>(ei, pos, edge_src);
    wprep_kernel<<<128, 128, 0, stream>>>(agg_W, agg_b, W, b, Wt2, cvec);
    gather_kernel<<<(N_NODES + 3) / 4, 256, 0, stream>>>(x, pos, deg_cnt, edge_src, out);
    gsage_main<<<(N_NODES + TM - 1) / TM, 256, 0, stream>>>(
        x, out, Wt2, cvec, gamma, beta, out);
}

// Round 6
// 304.503 us; speedup vs baseline: 5.0388x; 1.2738x over previous
//
#include <hip/hip_runtime.h>

#define N_NODES 50000
#define N_EDGES 800000
#define D_FEAT 128
#define LN_EPS 1e-5f
#define TM 32          // nodes per block in gsage_main
#define KB 32          // K-chunk
#define APAD 36        // padded A-tile row stride (floats), keeps 16B alignment
#define NBLK 196       // ceil(N_NODES/256) scan blocks

// ---------------------------------------------------------------------------
// zero the degree counters (ws is poisoned 0xAA every call)
// ---------------------------------------------------------------------------
__global__ void zero_kernel(int* __restrict__ p, int n)
{
    int i = blockIdx.x * 256 + threadIdx.x;
    if (i < n) p[i] = 0;
}

// ---------------------------------------------------------------------------
// histogram of destination nodes
// ---------------------------------------------------------------------------
__global__ void hist_kernel(const int* __restrict__ ei, int* __restrict__ deg_cnt)
{
    int e = blockIdx.x * 256 + threadIdx.x;
    if (e >= N_EDGES) return;
    int dst = ei[N_EDGES + e];
    dst = (dst < 0) ? 0 : ((dst >= N_NODES) ? (N_NODES - 1) : dst);
    atomicAdd(&deg_cnt[dst], 1);
}

// ---------------------------------------------------------------------------
// scan phase 1: per-block (256-elem chunk) sum of deg_cnt -> bsum[block]
// ---------------------------------------------------------------------------
__global__ void blocksum_kernel(const int* __restrict__ deg_cnt, int* __restrict__ bsum)
{
    __shared__ int ws[4];
    int b = blockIdx.x, t = threadIdx.x;
    int i = b * 256 + t;
    int v = (i < N_NODES) ? deg_cnt[i] : 0;
    #pragma unroll
    for (int off = 1; off < 64; off <<= 1) v += __shfl_xor(v, off, 64);
    if ((t & 63) == 0) ws[t >> 6] = v;
    __syncthreads();
    if (t == 0) bsum[b] = ws[0] + ws[1] + ws[2] + ws[3];
}

// ---------------------------------------------------------------------------
// scan phase 2: exclusive scan of the 196 block sums (single small block)
// ---------------------------------------------------------------------------
__global__ void scanblk_kernel(const int* __restrict__ bsum, int* __restrict__ boff)
{
    __shared__ int s[256];
    int t = threadIdx.x;
    int v = (t < NBLK) ? bsum[t] : 0;
    s[t] = v;
    __syncthreads();
    for (int off = 1; off < 256; off <<= 1) {
        int u = (t >= off) ? s[t - off] : 0;
        __syncthreads();
        s[t] += u;
        __syncthreads();
    }
    if (t < NBLK) boff[t] = s[t] - v;   // exclusive
}

// ---------------------------------------------------------------------------
// scan phase 3: block-local exclusive scan + block offset -> pos
// ---------------------------------------------------------------------------
__global__ void scanpos_kernel(const int* __restrict__ deg_cnt,
                               const int* __restrict__ boff,
                               int* __restrict__ pos)
{
    __shared__ int s[256];
    int b = blockIdx.x, t = threadIdx.x;
    int i = b * 256 + t;
    int v = (i < N_NODES) ? deg_cnt[i] : 0;
    s[t] = v;
    __syncthreads();
    for (int off = 1; off < 256; off <<= 1) {
        int u = (t >= off) ? s[t - off] : 0;
        __syncthreads();
        s[t] += u;
        __syncthreads();
    }
    if (i < N_NODES) pos[i] = boff[b] + s[t] - v;   // exclusive global
}

// ---------------------------------------------------------------------------
// bucket fill: edge_src[slot] = src, slot = pos[dst]++  (after this, pos = end)
// ---------------------------------------------------------------------------
__global__ void fill_kernel(const int* __restrict__ ei, int* __restrict__ pos,
                            int* __restrict__ edge_src)
{
    int e = blockIdx.x * 256 + threadIdx.x;
    if (e >= N_EDGES) return;
    int src = ei[e];
    int dst = ei[N_EDGES + e];
    src = (src < 0) ? 0 : ((src >= N_NODES) ? (N_NODES - 1) : src);
    dst = (dst < 0) ? 0 : ((dst >= N_NODES) ? (N_NODES - 1) : dst);
    int slot = atomicAdd(&pos[dst], 1);
    edge_src[slot] = src;
}

// ---------------------------------------------------------------------------
// gather: one 64-lane wave per node; agg mean written into d_out (scratch).
// Lane holds 2 features (float2); edge ids broadcast via shfl from a
// coalesced 64-edge batch load.
// ---------------------------------------------------------------------------
__global__ void gather_kernel(const float* __restrict__ x,
                              const int* __restrict__ pos,      // = end after fill
                              const int* __restrict__ deg_cnt,
                              const int* __restrict__ edge_src,
                              float* __restrict__ agg)          // d_out scratch
{
    int tid  = threadIdx.x;
    int node = blockIdx.x * 4 + (tid >> 6);
    int lane = tid & 63;
    if (node >= N_NODES) return;

    int end   = pos[node];
    int dcnt  = deg_cnt[node];
    int start = end - dcnt;

    float a0 = 0.0f, a1 = 0.0f;
    for (int b = start; b < end; b += 64) {
        int nb = end - b; if (nb > 64) nb = 64;
        int sid = (b + lane < end) ? edge_src[b + lane] : 0;
        for (int i = 0; i < nb; ++i) {
            int s = __shfl(sid, i, 64);
            const float2 v = *(const float2*)(x + (size_t)s * D_FEAT + lane * 2);
            a0 += v.x; a1 += v.y;
        }
    }
    float inv = 1.0f / (float)((dcnt > 1) ? dcnt : 1);
    agg[(size_t)node * D_FEAT + lane * 2]     = a0 * inv;
    agg[(size_t)node * D_FEAT + lane * 2 + 1] = a1 * inv;
}

// ---------------------------------------------------------------------------
// weight prep.  Wt2 layout [k][n], k<128 -> W1 (verbatim copy of W's first
// half); k>=128 -> M = agg_W @ W2.  Block t builds row t of both halves.
// Block 0 additionally builds cvec[n] = b[n] + sum_j agg_b[j]*W2[j][n].
// ---------------------------------------------------------------------------
__global__ void wprep_kernel(const float* __restrict__ agg_W,
                             const float* __restrict__ agg_b,
                             const float* __restrict__ W,
                             const float* __restrict__ b,
                             float* __restrict__ Wt2,
                             float* __restrict__ cvec)
{
    int t = blockIdx.x;    // 0..127
    int n = threadIdx.x;   // 0..127

    Wt2[t * 128 + n] = W[t * 128 + n];            // W1 half, already [k][n]

    float m = 0.0f;
    for (int j = 0; j < 128; ++j)
        m += agg_W[t * 128 + j] * W[(128 + j) * 128 + n];
    Wt2[(128 + t) * 128 + n] = m;

    if (t == 0) {
        float s = b[n];
        for (int j = 0; j < 128; ++j)
            s += agg_b[j] * W[(128 + j) * 128 + n];
        cvec[n] = s;
    }
}

// ---------------------------------------------------------------------------
// fused GEMM (A=[x|agg] @ Wt2^T + c) -> ReLU -> LayerNorm -> out (fp32).
// 256 threads, 32 nodes/block; K=256 chunked by 32; A + W chunks in LDS.
// Thread (tx=tid&31, ty=tid>>5) owns 4 nodes (ty*4..) x 4 cols (tx*4..).
// NOTE: reads agg rows from d_out and later overwrites the same rows; safe
// because each block only touches its own 32 nodes and all reads precede
// the epilogue stores.
// ---------------------------------------------------------------------------
__global__ __launch_bounds__(256) void gsage_main(
        const float* __restrict__ x,
        const float* __restrict__ agg,      // aliases `out`
        const float* __restrict__ Wt2,
        const float* __restrict__ cvec,
        const float* __restrict__ gamma,
        const float* __restrict__ beta,
        float* __restrict__ out)
{
    __shared__ float A[TM][APAD];     // 32 x 36 floats
    __shared__ float Wc[KB * 128];    // 32 x 128 floats

    int tid   = threadIdx.x;
    int tx    = tid & 31;
    int ty    = tid >> 5;
    int node0 = blockIdx.x * TM;

    float acc[4][4];
    #pragma unroll
    for (int i = 0; i < 4; ++i)
        #pragma unroll
        for (int j = 0; j < 4; ++j) acc[i][j] = 0.0f;

    for (int c = 0; c < 256 / KB; ++c) {
        int k0 = c * KB;
        // ---- stage A chunk: node = tid>>3, kk = (tid&7)*4 ----
        {
            int r  = tid >> 3;
            int kk = (tid & 7) * 4;
            int k  = k0 + kk;
            int node = node0 + r;
            float4 v = make_float4(0.f, 0.f, 0.f, 0.f);
            if (node < N_NODES) {
                const float* src = (k < 128)
                    ? (x   + (size_t)node * D_FEAT + k)
                    : (agg + (size_t)node * D_FEAT + (k - 128));
                v = *(const float4*)src;
            }
            *(float4*)&A[r][kk] = v;
        }
        // ---- stage W chunk: rows k0..k0+31 of Wt2, 16 KB contiguous ----
        {
            const float4* src = (const float4*)(Wt2 + k0 * 128);
            float4* dstp = (float4*)Wc;
            #pragma unroll
            for (int i = 0; i < 4; ++i)
                dstp[i * 256 + tid] = src[i * 256 + tid];
        }
        __syncthreads();

        // ---- inner product ----
        #pragma unroll 8
        for (int kk = 0; kk < KB; ++kk) {
            float a0 = A[ty * 4 + 0][kk];
            float a1 = A[ty * 4 + 1][kk];
            float a2 = A[ty * 4 + 2][kk];
            float a3 = A[ty * 4 + 3][kk];
            float4 w = *(const float4*)&Wc[kk * 128 + tx * 4];
            acc[0][0] += a0 * w.x; acc[0][1] += a0 * w.y; acc[0][2] += a0 * w.z; acc[0][3] += a0 * w.w;
            acc[1][0] += a1 * w.x; acc[1][1] += a1 * w.y; acc[1][2] += a1 * w.z; acc[1][3] += a1 * w.w;
            acc[2][0] += a2 * w.x; acc[2][1] += a2 * w.y; acc[2][2] += a2 * w.z; acc[2][3] += a2 * w.w;
            acc[3][0] += a3 * w.x; acc[3][1] += a3 * w.y; acc[3][2] += a3 * w.z; acc[3][3] += a3 * w.w;
        }
        __syncthreads();
    }

    // ---- epilogue: +c, ReLU, LayerNorm over 128 cols (32 tx lanes) ----
    float4 cv = *(const float4*)(cvec  + tx * 4);
    float4 gv = *(const float4*)(gamma + tx * 4);
    float4 bv = *(const float4*)(beta  + tx * 4);

    #pragma unroll
    for (int i = 0; i < 4; ++i) {
        float v0 = acc[i][0] + cv.x; v0 = (v0 > 0.f) ? v0 : 0.f;
        float v1 = acc[i][1] + cv.y; v1 = (v1 > 0.f) ? v1 : 0.f;
        float v2 = acc[i][2] + cv.z; v2 = (v2 > 0.f) ? v2 : 0.f;
        float v3 = acc[i][3] + cv.w; v3 = (v3 > 0.f) ? v3 : 0.f;
        float s1 = v0 + v1 + v2 + v3;
        float s2 = v0*v0 + v1*v1 + v2*v2 + v3*v3;
        #pragma unroll
        for (int m = 1; m < 32; m <<= 1) {
            s1 += __shfl_xor(s1, m, 64);
            s2 += __shfl_xor(s2, m, 64);
        }
        float mu  = s1 * (1.0f / 128.0f);
        float var = s2 * (1.0f / 128.0f) - mu * mu;
        float rstd = rsqrtf(var + LN_EPS);
        int node = node0 + ty * 4 + i;
        if (node < N_NODES) {
            float4 o;
            o.x = (v0 - mu) * rstd * gv.x + bv.x;
            o.y = (v1 - mu) * rstd * gv.y + bv.y;
            o.z = (v2 - mu) * rstd * gv.z + bv.z;
            o.w = (v3 - mu) * rstd * gv.w + bv.w;
            *(float4*)(out + (size_t)node * D_FEAT + tx * 4) = o;
        }
    }
}

// ---------------------------------------------------------------------------
extern "C" void kernel_launch(void* const* d_in, const int* in_sizes, int n_in,
                              void* d_out, int out_size, void* d_ws, size_t ws_size,
                              hipStream_t stream) {
    const float* x     = (const float*)d_in[0];
    const int*   ei    = (const int*)d_in[1];
    const float* agg_W = (const float*)d_in[2];
    const float* agg_b = (const float*)d_in[3];
    const float* W     = (const float*)d_in[4];
    const float* b     = (const float*)d_in[5];
    const float* gamma = (const float*)d_in[6];
    const float* beta  = (const float*)d_in[7];
    float*       out   = (float*)d_out;

    size_t out_bytes = (size_t)out_size * sizeof(float);

    if (n_in != 8)                       { hipMemsetAsync(d_out, 0x45, out_bytes, stream); return; }
    if (in_sizes[0] != N_NODES * D_FEAT) { hipMemsetAsync(d_out, 0x48, out_bytes, stream); return; }
    if (in_sizes[1] != 2 * N_EDGES)      { hipMemsetAsync(d_out, 0x49, out_bytes, stream); return; }
    if (out_size != N_NODES * D_FEAT)    { hipMemsetAsync(d_out, 0x47, out_bytes, stream); return; }

    // workspace layout (4-byte elements)
    int*   deg_cnt  = (int*)d_ws;                  // 50000
    int*   pos      = deg_cnt + N_NODES;           // 50000
    int*   edge_src = pos + N_NODES;               // 800000
    float* Wt2      = (float*)(edge_src + N_EDGES);// 256*128
    float* cvec     = Wt2 + 256 * 128;             // 128
    int*   bsum     = (int*)(cvec + 128);          // NBLK
    int*   boff     = bsum + NBLK;                 // NBLK
    size_t need_ws = ((size_t)N_NODES * 2 + N_EDGES + 256 * 128 + 128 + 2 * NBLK) * 4;
    if (ws_size < need_ws)               { hipMemsetAsync(d_out, 0x46, out_bytes, stream); return; }

    zero_kernel<<<(N_NODES + 255) / 256, 256, 0, stream>>>(deg_cnt, N_NODES);
    hist_kernel<<<(N_EDGES + 255) / 256, 256, 0, stream>>>(ei, deg_cnt);
    blocksum_kernel<<<NBLK, 256, 0, stream>>>(deg_cnt, bsum);
    scanblk_kernel<<<1, 256, 0, stream>>>(bsum, boff);
    scanpos_kernel<<<NBLK, 256, 0, stream>>>(deg_cnt, boff, pos);
    fill_kernel<<<(N_EDGES + 255) / 256, 256, 0, stream>>>(ei, pos, edge_src);
    wprep_kernel<<<128, 128, 0, stream>>>(agg_W, agg_b, W, b, Wt2, cvec);
    gather_kernel<<<(N_NODES + 3) / 4, 256, 0, stream>>>(x, pos, deg_cnt, edge_src, out);
    gsage_main<<<(N_NODES + TM - 1) / TM, 256, 0, stream>>>(
        x, out, Wt2, cvec, gamma, beta, out);
}